// Round 20
// baseline (132.041 us; speedup 1.0000x reference)
//
#include <hip/hip_runtime.h>
#include <hip/hip_bf16.h>

// GCN 2-layer forward: N=100000, E=3.2M, F_IN=256, HID=16, C=10.
// R20: k_bucket 512 WGs x 512 thr (2 WGs/CU: hist pass of one WG overlaps
// append pass of the other on the same CU's LDS-atomic/store pipes).
// k_gemm1 keep-alive asm removed (measured null-to-negative in R19).
// Everything else identical to R19 (returning-atomic rank sort, MFMA gemm,
// bf16-packed intermediates, register-staged aggregation).

#define F_IN 256
#define HID 16
#define NCLS 10
#define RB 128            // nodes per bucket
#define CAP 4608          // bucket capacity: mean 4092 + ~8 sigma
#define NBMAX 1024
#define OFFS 132          // stride of per-bucket offset table (>= RB+1)
#define UMASK 0x1FFFFFFu  // low 25 bits = source node id
#define SWEEPS 4
#define BKT_THR 512       // k_bucket threads per WG

typedef short short8 __attribute__((ext_vector_type(8)));
typedef float f32x4 __attribute__((ext_vector_type(4)));

__device__ __forceinline__ int eload(const void* ei, int idx, int is64) {
  return is64 ? (int)((const long long*)ei)[idx] : ((const int*)ei)[idx];
}

__device__ __forceinline__ unsigned pack_bf16(float a, float b) {
  unsigned ua = __float_as_uint(a), ub = __float_as_uint(b);
  ua = (ua + 0x7FFFu + ((ua >> 16) & 1)) >> 16;  // round-to-nearest-even
  ub = (ub + 0x7FFFu + ((ub >> 16) & 1)) >> 16;
  return ua | (ub << 16);
}

__device__ __forceinline__ unsigned cvtpk_bf16(float a, float b) {
  unsigned r;
  asm("v_cvt_pk_bf16_f32 %0, %1, %2" : "=v"(r) : "v"(a), "v"(b));
  return r;  // lo = bf16(a), hi = bf16(b), RNE — same as pack_bf16
}

__device__ __forceinline__ float2 unpack_bf16(unsigned w) {
  float2 r;
  r.x = __uint_as_float(w << 16);
  r.y = __uint_as_float(w & 0xFFFF0000u);
  return r;
}

// Fused prep: dtype detect (t0), cursor init (t<NB), W1 fragment bake (t<512).
__global__ __launch_bounds__(1024) void k_prep(const void* ei, int N, int* flag,
                                               int* cursor, int NB,
                                               const float* __restrict__ W1,
                                               unsigned* __restrict__ wfrag) {
  const int tid = threadIdx.x;
  if (tid == 0) {
    const unsigned long long* p = (const unsigned long long*)ei;
    int is64 = 1;
    for (int i = 0; i < 16; ++i) {
      if (p[i] >= (unsigned long long)N) { is64 = 0; break; }
    }
    *flag = is64;
  }
  if (tid < NB) cursor[tid] = tid * CAP;
  if (tid < 512) {
    int kk = tid >> 6, l = tid & 63;
    int g = l >> 4, n = l & 15;
    unsigned fr[4];
#pragma unroll
    for (int jp = 0; jp < 4; ++jp) {
      int j0 = 2 * jp, j1 = 2 * jp + 1;
      int k0 = kk * 32 + 4 * g + (j0 & 3) + 16 * (j0 >> 2);
      int k1 = kk * 32 + 4 * g + (j1 & 3) + 16 * (j1 >> 2);
      fr[jp] = pack_bf16(W1[k0 * HID + n], W1[k1 * HID + n]);
    }
    ((uint4*)wfrag)[kk * 64 + l] = make_uint4(fr[0], fr[1], fr[2], fr[3]);
  }
}

// Bucket edges by v>>7: register-staged single read; rank via returning hist
// atomic; append at reservation_base + rank (no second atomic, fast path).
// 512 WGs x 512 threads: two WGs per CU overlap hist(atomic) & append(store).
__global__ __launch_bounds__(BKT_THR) void k_bucket(const void* ei, int E,
                                                    const int* flag,
                                                    int* cursor,
                                                    unsigned* __restrict__ pk,
                                                    int NB) {
  __shared__ int hist[NBMAX];
  __shared__ int lpos[NBMAX];
  const int is64 = *flag;
  const int tid = threadIdx.x;
  for (int b = tid; b < NB; b += BKT_THR) hist[b] = 0;
  __syncthreads();

  const int t = blockIdx.x * BKT_THR + tid;
  const int nthr = gridDim.x * BKT_THR;
  const int ngroups = E >> 2;

  if (ngroups <= SWEEPS * nthr) {
    int u[SWEEPS][4], v[SWEEPS][4], rk[SWEEPS][4];
#pragma unroll
    for (int s = 0; s < SWEEPS; ++s) {
      const int g = t + s * nthr;
      if (g < ngroups) {
        const int e = g << 2;
        if (is64) {
          const long long* pu = (const long long*)ei;
          const long long* pv = pu + E;
          longlong2 a = *(const longlong2*)(pu + e);
          longlong2 b2 = *(const longlong2*)(pu + e + 2);
          longlong2 c = *(const longlong2*)(pv + e);
          longlong2 d = *(const longlong2*)(pv + e + 2);
          u[s][0] = (int)a.x; u[s][1] = (int)a.y;
          u[s][2] = (int)b2.x; u[s][3] = (int)b2.y;
          v[s][0] = (int)c.x; v[s][1] = (int)c.y;
          v[s][2] = (int)d.x; v[s][3] = (int)d.y;
        } else {
          int4 a = *(const int4*)((const int*)ei + e);
          int4 c = *(const int4*)((const int*)ei + E + e);
          u[s][0] = a.x; u[s][1] = a.y; u[s][2] = a.z; u[s][3] = a.w;
          v[s][0] = c.x; v[s][1] = c.y; v[s][2] = c.z; v[s][3] = c.w;
        }
#pragma unroll
        for (int j = 0; j < 4; ++j)
          rk[s][j] = atomicAdd(&hist[v[s][j] >> 7], 1);
      } else {
#pragma unroll
        for (int j = 0; j < 4; ++j) v[s][j] = -1;
      }
    }
    unsigned tw_u = 0; int tw_v = -1, tw_r = 0;
    if (blockIdx.x == 0 && tid < (E & 3)) {
      int e = (ngroups << 2) + tid;
      tw_u = (unsigned)eload(ei, e, is64);
      tw_v = eload(ei, E + e, is64);
      tw_r = atomicAdd(&hist[tw_v >> 7], 1);
    }
    __syncthreads();
    for (int b = tid; b < NB; b += BKT_THR) {
      int h = hist[b];
      lpos[b] = h ? atomicAdd(&cursor[b], h) : 0;  // base (NOT incremented)
    }
    __syncthreads();
#pragma unroll
    for (int s = 0; s < SWEEPS; ++s)
#pragma unroll
      for (int j = 0; j < 4; ++j)
        if (v[s][j] >= 0) {
          int b_ = v[s][j] >> 7;
          int p_ = lpos[b_] + rk[s][j];
          if (p_ < (b_ + 1) * CAP)
            pk[p_] = (unsigned)u[s][j] |
                     ((unsigned)(v[s][j] & (RB - 1)) << 25);
        }
    if (tw_v >= 0) {
      int b_ = tw_v >> 7;
      int p_ = lpos[b_] + tw_r;
      if (p_ < (b_ + 1) * CAP)
        pk[p_] = tw_u | ((unsigned)(tw_v & (RB - 1)) << 25);
    }
  } else {
    for (int k = t; k < E; k += nthr) {
      int v = eload(ei, E + k, is64);
      atomicAdd(&hist[v >> 7], 1);
    }
    __syncthreads();
    for (int b = tid; b < NB; b += BKT_THR) {
      int h = hist[b];
      lpos[b] = h ? atomicAdd(&cursor[b], h) : 0;
    }
    __syncthreads();
    for (int k = t; k < E; k += nthr) {
      int u = eload(ei, k, is64);
      int v = eload(ei, E + k, is64);
      int b_ = v >> 7;
      int p_ = atomicAdd(&lpos[b_], 1);
      if (p_ < (b_ + 1) * CAP)
        pk[p_] = (unsigned)u | ((unsigned)(v & (RB - 1)) << 25);
    }
  }
}

// Per-bucket counting sort via returning-atomic ranks (register-staged):
// sorted position = off + rank, written straight to global. Emits off_g, dis.
__global__ __launch_bounds__(512) void k_sortdeg(
    unsigned* __restrict__ pk, const int* __restrict__ cursor,
    int* __restrict__ off_g, float* __restrict__ dis, int N) {
  __shared__ int cnt[RB];
  __shared__ int off_l[RB + 1];
  const int b = blockIdx.x, tid = threadIdx.x;
  const int s = b * CAP;
  const int ne = min(cursor[b], s + CAP) - s;
  if (tid < RB) cnt[tid] = 0;
  __syncthreads();
  uint4 q[3];
  int rk[3][4];
  const int ne4 = ne >> 2;
  const uint4* pk4 = (const uint4*)(pk + s);
#pragma unroll
  for (int j = 0; j < 3; ++j) {
    const int gi = tid + j * 512;
    if (gi < ne4) {
      q[j] = pk4[gi];
      rk[j][0] = atomicAdd(&cnt[q[j].x >> 25], 1);
      rk[j][1] = atomicAdd(&cnt[q[j].y >> 25], 1);
      rk[j][2] = atomicAdd(&cnt[q[j].z >> 25], 1);
      rk[j][3] = atomicAdd(&cnt[q[j].w >> 25], 1);
    }
  }
  unsigned tw = 0;
  int tr = -1;
  {
    const int ti = (ne4 << 2) + tid;
    if (ti < ne) {
      tw = pk[s + ti];
      tr = atomicAdd(&cnt[tw >> 25], 1);
    }
  }
  __syncthreads();
  if (tid < 64) {
    int c0 = cnt[tid], c1 = cnt[tid + 64];
    int s0 = c0;
#pragma unroll
    for (int off = 1; off < 64; off <<= 1) {
      int t = __shfl_up(s0, off);
      if (tid >= off) s0 += t;
    }
    int tot0 = __shfl(s0, 63);
    int s1 = c1;
#pragma unroll
    for (int off = 1; off < 64; off <<= 1) {
      int t = __shfl_up(s1, off);
      if (tid >= off) s1 += t;
    }
    s1 += tot0;
    int e0 = s0 - c0, e1 = s1 - c1;  // exclusive prefix
    off_l[tid] = e0;
    off_l[tid + 64] = e1;
    off_g[b * OFFS + tid] = e0;
    off_g[b * OFFS + tid + 64] = e1;
    if (tid == 63) {
      off_l[RB] = s1;
      off_g[b * OFFS + RB] = s1;
    }
    int v0 = b * RB + tid, v1 = v0 + 64;
    if (v0 < N) dis[v0] = rsqrtf((float)c0 + 1.0f);
    if (v1 < N) dis[v1] = rsqrtf((float)c1 + 1.0f);
  }
  __syncthreads();
#pragma unroll
  for (int j = 0; j < 3; ++j) {
    const int gi = tid + j * 512;
    if (gi < ne4) {
      pk[s + off_l[q[j].x >> 25] + rk[j][0]] = q[j].x;
      pk[s + off_l[q[j].y >> 25] + rk[j][1]] = q[j].y;
      pk[s + off_l[q[j].z >> 25] + rk[j][2]] = q[j].z;
      pk[s + off_l[q[j].w >> 25] + rk[j][3]] = q[j].w;
    }
  }
  if (tr >= 0) pk[s + off_l[tw >> 25] + tr] = tw;
}

// h1p[v][p] = bf16pack((x[v]@W1)[2p..2p+1] * dis[v]) via MFMA, zero LDS.
__global__ __launch_bounds__(256) void k_gemm1(const float* __restrict__ x,
                                               const unsigned* __restrict__ wfrag,
                                               const float* __restrict__ dis,
                                               unsigned* __restrict__ h1p,
                                               int N) {
  const int tid = threadIdx.x;
  const int l = tid & 63, w = tid >> 6;
  const int g = l >> 4, m = l & 15;
  const int rowbase = blockIdx.x * 64 + w * 16;
  const float* xrow = x + (size_t)min(rowbase + m, N - 1) * F_IN;
  f32x4 acc = {0.f, 0.f, 0.f, 0.f};
#pragma unroll
  for (int kk = 0; kk < 8; ++kk) {
    const float4 xa = *(const float4*)(xrow + kk * 32 + 4 * g);
    const float4 xb = *(const float4*)(xrow + kk * 32 + 4 * g + 16);
    const uint4 bw = ((const uint4*)wfrag)[kk * 64 + l];
    union { unsigned u[4]; short8 s; } A, B;
    A.u[0] = cvtpk_bf16(xa.x, xa.y);
    A.u[1] = cvtpk_bf16(xa.z, xa.w);
    A.u[2] = cvtpk_bf16(xb.x, xb.y);
    A.u[3] = cvtpk_bf16(xb.z, xb.w);
    B.u[0] = bw.x; B.u[1] = bw.y; B.u[2] = bw.z; B.u[3] = bw.w;
    acc = __builtin_amdgcn_mfma_f32_16x16x32_bf16(A.s, B.s, acc, 0, 0, 0);
  }
  float dv[4];
  {
    const int base = rowbase + g * 4;
    if (base + 3 < N) {
      float4 d4 = *(const float4*)(dis + base);
      dv[0] = d4.x; dv[1] = d4.y; dv[2] = d4.z; dv[3] = d4.w;
    } else {
#pragma unroll
      for (int r = 0; r < 4; ++r) dv[r] = dis[min(base + r, N - 1)];
    }
  }
#pragma unroll
  for (int r = 0; r < 4; ++r) {
    int noder = rowbase + g * 4 + r;
    float v = acc[r] * dv[r];
    float pv = __shfl_xor(v, 1);  // partner col (m^1), same row
    if (!(l & 1) && noder < N) h1p[noder * 8 + (m >> 1)] = cvtpk_bf16(v, pv);
  }
}

// Layer-1 aggregate + finish, 1 WG/bucket. 128 groups x 4 lanes; lane p
// carries features 4p..4p+3 via one uint2 gather per edge.
__global__ __launch_bounds__(512) void k_bagg1(
    const unsigned* __restrict__ pk, const int* __restrict__ off_g,
    const unsigned* __restrict__ h1p, const float* __restrict__ dis,
    const float* __restrict__ W2, const float* __restrict__ b1,
    unsigned* __restrict__ h2p, int N) {
  __shared__ unsigned buf[CAP];
  __shared__ int off[RB + 1];
  __shared__ float st[RB * 17];
  __shared__ float w2s[HID * NCLS];
  __shared__ float b1s[HID];
  __shared__ unsigned st2[RB * 6];
  const int b = blockIdx.x, tid = threadIdx.x;
  const int s = b * CAP;
  const int ne = off_g[b * OFFS + RB];
  if (tid < HID * NCLS) w2s[tid] = W2[tid];
  if (tid < HID) b1s[tid] = b1[tid];
  if (tid <= RB) off[tid] = off_g[b * OFFS + tid];
  {
    const uint4* pk4 = (const uint4*)(pk + s);
    const int ne4 = ne >> 2;
    for (int i = tid; i < ne4; i += 512) ((uint4*)buf)[i] = pk4[i];
    for (int i = (ne4 << 2) + tid; i < ne; i += 512) buf[i] = pk[s + i];
  }
  __syncthreads();
  const int lv = tid >> 2, p = tid & 3;   // 128 groups x 4 lanes
  const uint2* h1u2 = (const uint2*)h1p;  // 4 uint2 per node row
  {
    const int k0 = off[lv], k1 = off[lv + 1];
    float a0 = 0.f, a1 = 0.f, a2 = 0.f, a3 = 0.f;
    float c0 = 0.f, c1 = 0.f, c2 = 0.f, c3 = 0.f;
    int k = k0;
    for (; k + 1 < k1; k += 2) {  // 2 gathers in flight
      int u0 = (int)(buf[k] & UMASK), u1 = (int)(buf[k + 1] & UMASK);
      uint2 q0 = h1u2[(u0 << 2) + p];
      uint2 q1 = h1u2[(u1 << 2) + p];
      float2 f00 = unpack_bf16(q0.x), f01 = unpack_bf16(q0.y);
      float2 f10 = unpack_bf16(q1.x), f11 = unpack_bf16(q1.y);
      a0 += f00.x; a1 += f00.y; a2 += f01.x; a3 += f01.y;
      c0 += f10.x; c1 += f10.y; c2 += f11.x; c3 += f11.y;
    }
    if (k < k1) {
      int u0 = (int)(buf[k] & UMASK);
      uint2 q0 = h1u2[(u0 << 2) + p];
      float2 f00 = unpack_bf16(q0.x), f01 = unpack_bf16(q0.y);
      a0 += f00.x; a1 += f00.y; a2 += f01.x; a3 += f01.y;
    }
    st[lv * 17 + 4 * p + 0] = a0 + c0;
    st[lv * 17 + 4 * p + 1] = a1 + c1;
    st[lv * 17 + 4 * p + 2] = a2 + c2;
    st[lv * 17 + 4 * p + 3] = a3 + c3;
  }
  __syncthreads();
  if (tid < RB) {
    int v = b * RB + tid;
    if (v < N) {
      float d = dis[v];
      float a[HID];
#pragma unroll
      for (int q = 0; q < 8; ++q) {
        float2 sf = unpack_bf16(h1p[(v << 3) + q]);
        float t0 = d * (st[tid * 17 + 2 * q] + sf.x) + b1s[2 * q];
        float t1 = d * (st[tid * 17 + 2 * q + 1] + sf.y) + b1s[2 * q + 1];
        a[2 * q] = t0 > 0.f ? t0 : 0.f;
        a[2 * q + 1] = t1 > 0.f ? t1 : 0.f;
      }
#pragma unroll
      for (int c = 0; c < 5; ++c) {
        float s0 = 0.f, s1 = 0.f;
#pragma unroll
        for (int jj = 0; jj < HID; ++jj) {
          s0 = fmaf(a[jj], w2s[jj * NCLS + 2 * c], s0);
          s1 = fmaf(a[jj], w2s[jj * NCLS + 2 * c + 1], s1);
        }
        st2[tid * 6 + c] = pack_bf16(s0 * d, s1 * d);
      }
      st2[tid * 6 + 5] = 0u;  // pad pair (features 10,11)
    }
  }
  __syncthreads();
  int nn = min(RB, N - b * RB);
  if (nn < 0) nn = 0;
  const int tot = nn * 6;
  const int obase = b * RB * 6;
  {
    const int tot4 = tot >> 2;
    uint4* o4 = (uint4*)(h2p + obase);
    for (int i = tid; i < tot4; i += 512) o4[i] = ((const uint4*)st2)[i];
    for (int i = (tot4 << 2) + tid; i < tot; i += 512)
      h2p[obase + i] = st2[i];
  }
}

// Layer-2 aggregate + finish + log_softmax, 1 WG/bucket. 128 groups x 4
// lanes; lanes p<3 gather uint2 (features 4p..4p+3; 10,11 are zero pads).
__global__ __launch_bounds__(512) void k_bagg2(
    const unsigned* __restrict__ pk, const int* __restrict__ off_g,
    const unsigned* __restrict__ h2p, const float* __restrict__ dis,
    const float* __restrict__ b2, float* __restrict__ out, int N) {
  __shared__ unsigned buf[CAP];
  __shared__ int off[RB + 1];
  __shared__ float st[RB * 13];
  __shared__ float b2s[NCLS];
  __shared__ float sto[RB * NCLS];
  const int b = blockIdx.x, tid = threadIdx.x;
  const int s = b * CAP;
  const int ne = off_g[b * OFFS + RB];
  if (tid < NCLS) b2s[tid] = b2[tid];
  if (tid <= RB) off[tid] = off_g[b * OFFS + tid];
  {
    const uint4* pk4 = (const uint4*)(pk + s);
    const int ne4 = ne >> 2;
    for (int i = tid; i < ne4; i += 512) ((uint4*)buf)[i] = pk4[i];
    for (int i = (ne4 << 2) + tid; i < ne; i += 512) buf[i] = pk[s + i];
  }
  __syncthreads();
  const int lv = tid >> 2, p = tid & 3;   // 128 groups x 4 lanes (p<3 active)
  const uint2* h2u2 = (const uint2*)h2p;  // 3 uint2 per node row
  if (p < 3) {
    const int k0 = off[lv], k1 = off[lv + 1];
    float a0 = 0.f, a1 = 0.f, a2 = 0.f, a3 = 0.f;
    float c0 = 0.f, c1 = 0.f, c2 = 0.f, c3 = 0.f;
    int k = k0;
    for (; k + 1 < k1; k += 2) {
      int u0 = (int)(buf[k] & UMASK), u1 = (int)(buf[k + 1] & UMASK);
      uint2 q0 = h2u2[u0 * 3 + p];
      uint2 q1 = h2u2[u1 * 3 + p];
      float2 f00 = unpack_bf16(q0.x), f01 = unpack_bf16(q0.y);
      float2 f10 = unpack_bf16(q1.x), f11 = unpack_bf16(q1.y);
      a0 += f00.x; a1 += f00.y; a2 += f01.x; a3 += f01.y;
      c0 += f10.x; c1 += f10.y; c2 += f11.x; c3 += f11.y;
    }
    if (k < k1) {
      int u0 = (int)(buf[k] & UMASK);
      uint2 q0 = h2u2[u0 * 3 + p];
      float2 f00 = unpack_bf16(q0.x), f01 = unpack_bf16(q0.y);
      a0 += f00.x; a1 += f00.y; a2 += f01.x; a3 += f01.y;
    }
    st[lv * 13 + 4 * p + 0] = a0 + c0;
    st[lv * 13 + 4 * p + 1] = a1 + c1;
    st[lv * 13 + 4 * p + 2] = a2 + c2;
    st[lv * 13 + 4 * p + 3] = a3 + c3;
  }
  __syncthreads();
  if (tid < RB) {
    int v = b * RB + tid;
    if (v < N) {
      float d = dis[v];
      float vals[NCLS];
      float m = -1e30f;
#pragma unroll
      for (int c = 0; c < 5; ++c) {
        float2 sf = unpack_bf16(h2p[v * 6 + c]);
        float t0 = d * (st[tid * 13 + 2 * c] + sf.x) + b2s[2 * c];
        float t1 = d * (st[tid * 13 + 2 * c + 1] + sf.y) + b2s[2 * c + 1];
        vals[2 * c] = t0;
        vals[2 * c + 1] = t1;
        m = fmaxf(m, fmaxf(t0, t1));
      }
      float sum = 0.f;
#pragma unroll
      for (int c = 0; c < NCLS; ++c) sum += expf(vals[c] - m);
      float ls = logf(sum);
#pragma unroll
      for (int c = 0; c < NCLS; ++c) sto[tid * NCLS + c] = vals[c] - m - ls;
    }
  }
  __syncthreads();
  int nn = min(RB, N - b * RB);
  if (nn < 0) nn = 0;
  const int tot = nn * NCLS;
  const int obase = b * RB * NCLS;
  {
    const int tot4 = tot >> 2;
    float4* o4 = (float4*)(out + obase);
    for (int i = tid; i < tot4; i += 512) o4[i] = ((const float4*)sto)[i];
    for (int i = (tot4 << 2) + tid; i < tot; i += 512)
      out[obase + i] = sto[i];
  }
}

extern "C" void kernel_launch(void* const* d_in, const int* in_sizes, int n_in,
                              void* d_out, int out_size, void* d_ws,
                              size_t ws_size, hipStream_t stream) {
  const float* x = (const float*)d_in[0];
  const void* ei = d_in[1];
  const float* W1 = (const float*)d_in[2];
  const float* b1 = (const float*)d_in[3];
  const float* W2 = (const float*)d_in[4];
  const float* b2 = (const float*)d_in[5];
  float* out = (float*)d_out;

  const int N = in_sizes[0] / F_IN;  // 100000
  const int E = in_sizes[1] / 2;     // 3200000
  const int NB = (N + RB - 1) / RB;  // 782 buckets
  const int NPAD = NB * RB;

  // ws layout (4-byte words):
  int* flag = (int*)d_ws;                      // [16]
  int* cursor = flag + 16;                     // [NBMAX]
  unsigned* wfrag = (unsigned*)(cursor + NBMAX);  // [2048] 8KB W1 fragments
  unsigned* pk = wfrag + 2048;                 // [NB*CAP] ~14.4 MB
  int* off_g = (int*)(pk + (long long)NB * CAP);  // [NB*OFFS] ~0.4 MB
  float* dis = (float*)(off_g + (long long)NB * OFFS);  // [NPAD]
  unsigned* h1p = (unsigned*)(dis + NPAD);     // [8*NPAD] 3.2 MB (bf16 x16)
  unsigned* h2p = h1p + (long long)8 * NPAD;   // [6*NPAD] 2.4 MB (bf16 x12)
  // total ~21.5 MB

  k_prep<<<1, 1024, 0, stream>>>(ei, N, flag, cursor, NB, W1, wfrag);
  k_bucket<<<512, BKT_THR, 0, stream>>>(ei, E, flag, cursor, pk, NB);
  k_sortdeg<<<NB, 512, 0, stream>>>(pk, cursor, off_g, dis, N);
  k_gemm1<<<(N + 63) / 64, 256, 0, stream>>>(x, wfrag, dis, h1p, N);
  k_bagg1<<<NB, 512, 0, stream>>>(pk, off_g, h1p, dis, W2, b1, h2p, N);
  k_bagg2<<<NB, 512, 0, stream>>>(pk, off_g, h2p, dis, b2, out, N);
}

// Round 21
// 124.954 us; speedup vs baseline: 1.0567x; 1.0567x over previous
//
#include <hip/hip_runtime.h>
#include <hip/hip_bf16.h>

// GCN 2-layer forward: N=100000, E=3.2M, F_IN=256, HID=16, C=10.
// R21: revert to the best-measured configuration (R13, 124.99 us):
// fused k_sortgemm (sort + dis + MFMA gemm) with LDS-only barriers,
// k_bucket 256x1024 register-staged, uint2-gather bagg1/bagg2.
// R14-R20 variants (asm prefetch, rank trick in bucket, MLP forcing,
// WG splits) all measured null-to-negative and are dropped.

#define F_IN 256
#define HID 16
#define NCLS 10
#define RB 128            // nodes per bucket
#define CAP 4608          // bucket capacity: mean 4092 + ~8 sigma
#define NBMAX 1024
#define OFFS 132          // stride of per-bucket offset table (>= RB+1)
#define UMASK 0x1FFFFFFu  // low 25 bits = source node id
#define SWEEPS 4

// LDS-only barrier: orders LDS ops across the WG WITHOUT draining vmcnt.
#define BAR_LDS()                                        \
  do {                                                   \
    asm volatile("s_waitcnt lgkmcnt(0)" ::: "memory");   \
    __builtin_amdgcn_sched_barrier(0);                   \
    __builtin_amdgcn_s_barrier();                        \
    __builtin_amdgcn_sched_barrier(0);                   \
  } while (0)

typedef short short8 __attribute__((ext_vector_type(8)));
typedef float f32x4 __attribute__((ext_vector_type(4)));

__device__ __forceinline__ int eload(const void* ei, int idx, int is64) {
  return is64 ? (int)((const long long*)ei)[idx] : ((const int*)ei)[idx];
}

__device__ __forceinline__ unsigned pack_bf16(float a, float b) {
  unsigned ua = __float_as_uint(a), ub = __float_as_uint(b);
  ua = (ua + 0x7FFFu + ((ua >> 16) & 1)) >> 16;  // round-to-nearest-even
  ub = (ub + 0x7FFFu + ((ub >> 16) & 1)) >> 16;
  return ua | (ub << 16);
}

__device__ __forceinline__ unsigned cvtpk_bf16(float a, float b) {
  unsigned r;
  asm("v_cvt_pk_bf16_f32 %0, %1, %2" : "=v"(r) : "v"(a), "v"(b));
  return r;  // lo = bf16(a), hi = bf16(b), RNE — same as pack_bf16
}

__device__ __forceinline__ float2 unpack_bf16(unsigned w) {
  float2 r;
  r.x = __uint_as_float(w << 16);
  r.y = __uint_as_float(w & 0xFFFF0000u);
  return r;
}

// Fused prep: dtype detect (t0), cursor init (t<NB), W1 fragment bake (t<512).
__global__ __launch_bounds__(1024) void k_prep(const void* ei, int N, int* flag,
                                               int* cursor, int NB,
                                               const float* __restrict__ W1,
                                               unsigned* __restrict__ wfrag) {
  const int tid = threadIdx.x;
  if (tid == 0) {
    const unsigned long long* p = (const unsigned long long*)ei;
    int is64 = 1;
    for (int i = 0; i < 16; ++i) {
      if (p[i] >= (unsigned long long)N) { is64 = 0; break; }
    }
    *flag = is64;
  }
  if (tid < NB) cursor[tid] = tid * CAP;
  if (tid < 512) {
    int kk = tid >> 6, l = tid & 63;
    int g = l >> 4, n = l & 15;
    unsigned fr[4];
#pragma unroll
    for (int jp = 0; jp < 4; ++jp) {
      int j0 = 2 * jp, j1 = 2 * jp + 1;
      int k0 = kk * 32 + 4 * g + (j0 & 3) + 16 * (j0 >> 2);
      int k1 = kk * 32 + 4 * g + (j1 & 3) + 16 * (j1 >> 2);
      fr[jp] = pack_bf16(W1[k0 * HID + n], W1[k1 * HID + n]);
    }
    ((uint4*)wfrag)[kk * 64 + l] = make_uint4(fr[0], fr[1], fr[2], fr[3]);
  }
}

// Bucket edges by v>>7: single global read (register-staged, 16 edges/thread),
// LDS histogram -> one reservation atomic per bucket -> appends at lpos[b]++.
__global__ __launch_bounds__(1024) void k_bucket(const void* ei, int E,
                                                 const int* flag, int* cursor,
                                                 unsigned* __restrict__ pk,
                                                 int NB) {
  __shared__ int hist[NBMAX];
  __shared__ int lpos[NBMAX];
  const int is64 = *flag;
  const int tid = threadIdx.x;
  for (int b = tid; b < NB; b += 1024) hist[b] = 0;
  __syncthreads();

  const int t = blockIdx.x * 1024 + tid;
  const int nthr = gridDim.x * 1024;
  const int ngroups = E >> 2;
  int u[SWEEPS][4], v[SWEEPS][4];
#pragma unroll
  for (int s = 0; s < SWEEPS; ++s) {
    const int g = t + s * nthr;
    if (g < ngroups) {
      const int e = g << 2;
      if (is64) {
        const long long* pu = (const long long*)ei;
        const long long* pv = pu + E;
        longlong2 a = *(const longlong2*)(pu + e);
        longlong2 b2 = *(const longlong2*)(pu + e + 2);
        longlong2 c = *(const longlong2*)(pv + e);
        longlong2 d = *(const longlong2*)(pv + e + 2);
        u[s][0] = (int)a.x; u[s][1] = (int)a.y;
        u[s][2] = (int)b2.x; u[s][3] = (int)b2.y;
        v[s][0] = (int)c.x; v[s][1] = (int)c.y;
        v[s][2] = (int)d.x; v[s][3] = (int)d.y;
      } else {
        int4 a = *(const int4*)((const int*)ei + e);
        int4 c = *(const int4*)((const int*)ei + E + e);
        u[s][0] = a.x; u[s][1] = a.y; u[s][2] = a.z; u[s][3] = a.w;
        v[s][0] = c.x; v[s][1] = c.y; v[s][2] = c.z; v[s][3] = c.w;
      }
    } else {
#pragma unroll
      for (int j = 0; j < 4; ++j) v[s][j] = -1;  // invalid marker
    }
  }
#pragma unroll
  for (int s = 0; s < SWEEPS; ++s)
#pragma unroll
    for (int j = 0; j < 4; ++j)
      if (v[s][j] >= 0) atomicAdd(&hist[v[s][j] >> 7], 1);
  for (int g = t + SWEEPS * nthr; g < ngroups; g += nthr) {
    const int e = g << 2;
#pragma unroll
    for (int j = 0; j < 4; ++j)
      atomicAdd(&hist[eload(ei, E + e + j, is64) >> 7], 1);
  }
  if (blockIdx.x == 0 && tid < (E & 3))
    atomicAdd(&hist[eload(ei, E + (ngroups << 2) + tid, is64) >> 7], 1);
  __syncthreads();
  for (int b = tid; b < NB; b += 1024) {
    int h = hist[b];
    lpos[b] = h ? atomicAdd(&cursor[b], h) : 0;  // absolute base position
  }
  __syncthreads();
#define APP(uu, vv)                                                     \
  {                                                                     \
    int b_ = (vv) >> 7;                                                 \
    int p_ = atomicAdd(&lpos[b_], 1);                                   \
    if (p_ < (b_ + 1) * CAP)                                            \
      pk[p_] = (unsigned)(uu) | ((unsigned)((vv) & (RB - 1)) << 25);    \
  }
#pragma unroll
  for (int s = 0; s < SWEEPS; ++s)
#pragma unroll
    for (int j = 0; j < 4; ++j)
      if (v[s][j] >= 0) APP(u[s][j], v[s][j])
  for (int g = t + SWEEPS * nthr; g < ngroups; g += nthr) {
    const int e = g << 2;
#pragma unroll
    for (int j = 0; j < 4; ++j) {
      int uu = eload(ei, e + j, is64);
      int vv = eload(ei, E + e + j, is64);
      APP(uu, vv)
    }
  }
  if (blockIdx.x == 0 && tid < (E & 3)) {
    int e = (ngroups << 2) + tid;
    int uu = eload(ei, e, is64);
    int vv = eload(ei, E + e, is64);
    APP(uu, vv)
  }
#undef APP
}

// FUSED: per-bucket counting sort + dis + MFMA gemm, with the x-stream
// issued before the sort's LDS-only barriers so HBM streams under the sort.
__global__ __launch_bounds__(512) void k_sortgemm(
    unsigned* __restrict__ pk, const int* __restrict__ cursor,
    int* __restrict__ off_g, float* __restrict__ dis,
    const float* __restrict__ x, const unsigned* __restrict__ wfrag,
    unsigned* __restrict__ h1p, int N) {
  __shared__ unsigned buf[CAP];
  __shared__ int cnt[RB];
  __shared__ int scn[RB];
  __shared__ int cur[RB + 1];
  __shared__ float dis_l[RB];
  const int b = blockIdx.x, tid = threadIdx.x;
  const int s = b * CAP;
  const int ne = min(cursor[b], s + CAP) - s;
  // gemm-phase indices (needed for the early x loads)
  const int l = tid & 63, wv = tid >> 6;
  const int g = l >> 4, m = l & 15;
  const int nlocal = wv * 16;
  const int rowbase = b * RB + nlocal;
  const float* xrow = x + (size_t)min(rowbase + m, N - 1) * F_IN;

  if (tid < RB) cnt[tid] = 0;
  // pk staging loads FIRST (oldest in vmcnt FIFO -> their waits don't drain x)
  {
    const uint4* pk4 = (const uint4*)(pk + s);
    const int ne4 = ne >> 2;
    for (int i = tid; i < ne4; i += 512) ((uint4*)buf)[i] = pk4[i];
    for (int i = (ne4 << 2) + tid; i < ne; i += 512) buf[i] = pk[s + i];
  }
  // issue first half of the x-stream now; stays in flight across the sort
  float4 xv[8];
#pragma unroll
  for (int kk = 0; kk < 4; ++kk) {
    xv[2 * kk] = *(const float4*)(xrow + kk * 32 + 4 * g);
    xv[2 * kk + 1] = *(const float4*)(xrow + kk * 32 + 4 * g + 16);
  }
  BAR_LDS();
  for (int i = tid; i < ne; i += 512) atomicAdd(&cnt[buf[i] >> 25], 1);
  BAR_LDS();
  if (tid < RB) scn[tid] = cnt[tid];
  BAR_LDS();
#pragma unroll
  for (int off = 1; off < RB; off <<= 1) {
    int t = (tid < RB && tid >= off) ? scn[tid - off] : 0;
    BAR_LDS();
    if (tid < RB) scn[tid] += t;
    BAR_LDS();
  }
  if (tid < RB) cur[tid] = scn[tid] - cnt[tid];  // exclusive
  BAR_LDS();
  if (tid == 0) cur[RB] = scn[RB - 1];
  BAR_LDS();
  if (tid <= RB) off_g[b * OFFS + tid] = cur[tid];
  if (tid < RB) {
    float dv = rsqrtf((float)cnt[tid] + 1.0f);
    dis_l[tid] = dv;
    int v = b * RB + tid;
    if (v < N) dis[v] = dv;
  }
  BAR_LDS();  // off snapshot + dis_l ready before cur is consumed
  for (int i = tid; i < ne; i += 512) {
    unsigned w = buf[i];
    int pos = atomicAdd(&cur[w >> 25], 1);
    pk[s + pos] = w;  // in-place safe: whole bucket already staged in LDS
  }
  // NO barrier: gemm reads only dis_l (ordered above) and its own loads.
  f32x4 acc = {0.f, 0.f, 0.f, 0.f};
#pragma unroll
  for (int kk = 0; kk < 4; ++kk) {
    const uint4 bw = ((const uint4*)wfrag)[kk * 64 + l];
    union { unsigned u[4]; short8 s; } A, B;
    A.u[0] = cvtpk_bf16(xv[2 * kk].x, xv[2 * kk].y);
    A.u[1] = cvtpk_bf16(xv[2 * kk].z, xv[2 * kk].w);
    A.u[2] = cvtpk_bf16(xv[2 * kk + 1].x, xv[2 * kk + 1].y);
    A.u[3] = cvtpk_bf16(xv[2 * kk + 1].z, xv[2 * kk + 1].w);
    B.u[0] = bw.x; B.u[1] = bw.y; B.u[2] = bw.z; B.u[3] = bw.w;
    acc = __builtin_amdgcn_mfma_f32_16x16x32_bf16(A.s, B.s, acc, 0, 0, 0);
  }
#pragma unroll
  for (int kk = 4; kk < 8; ++kk) {
    const float4 xa = *(const float4*)(xrow + kk * 32 + 4 * g);
    const float4 xb = *(const float4*)(xrow + kk * 32 + 4 * g + 16);
    const uint4 bw = ((const uint4*)wfrag)[kk * 64 + l];
    union { unsigned u[4]; short8 s; } A, B;
    A.u[0] = cvtpk_bf16(xa.x, xa.y);
    A.u[1] = cvtpk_bf16(xa.z, xa.w);
    A.u[2] = cvtpk_bf16(xb.x, xb.y);
    A.u[3] = cvtpk_bf16(xb.z, xb.w);
    B.u[0] = bw.x; B.u[1] = bw.y; B.u[2] = bw.z; B.u[3] = bw.w;
    acc = __builtin_amdgcn_mfma_f32_16x16x32_bf16(A.s, B.s, acc, 0, 0, 0);
  }
#pragma unroll
  for (int r = 0; r < 4; ++r) {
    int noder = rowbase + g * 4 + r;
    float v = acc[r] * dis_l[nlocal + g * 4 + r];
    float pv = __shfl_xor(v, 1);  // partner col (m^1), same row
    if (!(l & 1) && noder < N) h1p[noder * 8 + (m >> 1)] = cvtpk_bf16(v, pv);
  }
}

// Layer-1 aggregate + finish, 1 WG/bucket. 128 groups x 4 lanes; lane p
// carries features 4p..4p+3 via one uint2 gather per edge.
__global__ __launch_bounds__(512) void k_bagg1(
    const unsigned* __restrict__ pk, const int* __restrict__ off_g,
    const unsigned* __restrict__ h1p, const float* __restrict__ dis,
    const float* __restrict__ W2, const float* __restrict__ b1,
    unsigned* __restrict__ h2p, int N) {
  __shared__ unsigned buf[CAP];
  __shared__ int off[RB + 1];
  __shared__ float st[RB * 17];
  __shared__ float w2s[HID * NCLS];
  __shared__ float b1s[HID];
  __shared__ unsigned st2[RB * 6];
  const int b = blockIdx.x, tid = threadIdx.x;
  const int s = b * CAP;
  const int ne = off_g[b * OFFS + RB];
  if (tid < HID * NCLS) w2s[tid] = W2[tid];
  if (tid < HID) b1s[tid] = b1[tid];
  if (tid <= RB) off[tid] = off_g[b * OFFS + tid];
  {
    const uint4* pk4 = (const uint4*)(pk + s);
    const int ne4 = ne >> 2;
    for (int i = tid; i < ne4; i += 512) ((uint4*)buf)[i] = pk4[i];
    for (int i = (ne4 << 2) + tid; i < ne; i += 512) buf[i] = pk[s + i];
  }
  __syncthreads();
  const int lv = tid >> 2, p = tid & 3;   // 128 groups x 4 lanes
  const uint2* h1u2 = (const uint2*)h1p;  // 4 uint2 per node row
  {
    const int k0 = off[lv], k1 = off[lv + 1];
    float a0 = 0.f, a1 = 0.f, a2 = 0.f, a3 = 0.f;
    float c0 = 0.f, c1 = 0.f, c2 = 0.f, c3 = 0.f;
    int k = k0;
    for (; k + 1 < k1; k += 2) {  // 2 gathers in flight
      int u0 = (int)(buf[k] & UMASK), u1 = (int)(buf[k + 1] & UMASK);
      uint2 q0 = h1u2[(u0 << 2) + p];
      uint2 q1 = h1u2[(u1 << 2) + p];
      float2 f00 = unpack_bf16(q0.x), f01 = unpack_bf16(q0.y);
      float2 f10 = unpack_bf16(q1.x), f11 = unpack_bf16(q1.y);
      a0 += f00.x; a1 += f00.y; a2 += f01.x; a3 += f01.y;
      c0 += f10.x; c1 += f10.y; c2 += f11.x; c3 += f11.y;
    }
    if (k < k1) {
      int u0 = (int)(buf[k] & UMASK);
      uint2 q0 = h1u2[(u0 << 2) + p];
      float2 f00 = unpack_bf16(q0.x), f01 = unpack_bf16(q0.y);
      a0 += f00.x; a1 += f00.y; a2 += f01.x; a3 += f01.y;
    }
    st[lv * 17 + 4 * p + 0] = a0 + c0;
    st[lv * 17 + 4 * p + 1] = a1 + c1;
    st[lv * 17 + 4 * p + 2] = a2 + c2;
    st[lv * 17 + 4 * p + 3] = a3 + c3;
  }
  __syncthreads();
  if (tid < RB) {
    int v = b * RB + tid;
    if (v < N) {
      float d = dis[v];
      float a[HID];
#pragma unroll
      for (int q = 0; q < 8; ++q) {
        float2 sf = unpack_bf16(h1p[(v << 3) + q]);
        float t0 = d * (st[tid * 17 + 2 * q] + sf.x) + b1s[2 * q];
        float t1 = d * (st[tid * 17 + 2 * q + 1] + sf.y) + b1s[2 * q + 1];
        a[2 * q] = t0 > 0.f ? t0 : 0.f;
        a[2 * q + 1] = t1 > 0.f ? t1 : 0.f;
      }
#pragma unroll
      for (int c = 0; c < 5; ++c) {
        float s0 = 0.f, s1 = 0.f;
#pragma unroll
        for (int jj = 0; jj < HID; ++jj) {
          s0 = fmaf(a[jj], w2s[jj * NCLS + 2 * c], s0);
          s1 = fmaf(a[jj], w2s[jj * NCLS + 2 * c + 1], s1);
        }
        st2[tid * 6 + c] = pack_bf16(s0 * d, s1 * d);
      }
      st2[tid * 6 + 5] = 0u;  // pad pair (features 10,11)
    }
  }
  __syncthreads();
  int nn = min(RB, N - b * RB);
  if (nn < 0) nn = 0;
  const int tot = nn * 6;
  const int obase = b * RB * 6;
  {
    const int tot4 = tot >> 2;
    uint4* o4 = (uint4*)(h2p + obase);
    for (int i = tid; i < tot4; i += 512) o4[i] = ((const uint4*)st2)[i];
    for (int i = (tot4 << 2) + tid; i < tot; i += 512)
      h2p[obase + i] = st2[i];
  }
}

// Layer-2 aggregate + finish + log_softmax, 1 WG/bucket. 128 groups x 4
// lanes; lanes p<3 gather uint2 (features 4p..4p+3; 10,11 are zero pads).
__global__ __launch_bounds__(512) void k_bagg2(
    const unsigned* __restrict__ pk, const int* __restrict__ off_g,
    const unsigned* __restrict__ h2p, const float* __restrict__ dis,
    const float* __restrict__ b2, float* __restrict__ out, int N) {
  __shared__ unsigned buf[CAP];
  __shared__ int off[RB + 1];
  __shared__ float st[RB * 13];
  __shared__ float b2s[NCLS];
  __shared__ float sto[RB * NCLS];
  const int b = blockIdx.x, tid = threadIdx.x;
  const int s = b * CAP;
  const int ne = off_g[b * OFFS + RB];
  if (tid < NCLS) b2s[tid] = b2[tid];
  if (tid <= RB) off[tid] = off_g[b * OFFS + tid];
  {
    const uint4* pk4 = (const uint4*)(pk + s);
    const int ne4 = ne >> 2;
    for (int i = tid; i < ne4; i += 512) ((uint4*)buf)[i] = pk4[i];
    for (int i = (ne4 << 2) + tid; i < ne; i += 512) buf[i] = pk[s + i];
  }
  __syncthreads();
  const int lv = tid >> 2, p = tid & 3;   // 128 groups x 4 lanes (p<3 active)
  const uint2* h2u2 = (const uint2*)h2p;  // 3 uint2 per node row
  if (p < 3) {
    const int k0 = off[lv], k1 = off[lv + 1];
    float a0 = 0.f, a1 = 0.f, a2 = 0.f, a3 = 0.f;
    float c0 = 0.f, c1 = 0.f, c2 = 0.f, c3 = 0.f;
    int k = k0;
    for (; k + 1 < k1; k += 2) {
      int u0 = (int)(buf[k] & UMASK), u1 = (int)(buf[k + 1] & UMASK);
      uint2 q0 = h2u2[u0 * 3 + p];
      uint2 q1 = h2u2[u1 * 3 + p];
      float2 f00 = unpack_bf16(q0.x), f01 = unpack_bf16(q0.y);
      float2 f10 = unpack_bf16(q1.x), f11 = unpack_bf16(q1.y);
      a0 += f00.x; a1 += f00.y; a2 += f01.x; a3 += f01.y;
      c0 += f10.x; c1 += f10.y; c2 += f11.x; c3 += f11.y;
    }
    if (k < k1) {
      int u0 = (int)(buf[k] & UMASK);
      uint2 q0 = h2u2[u0 * 3 + p];
      float2 f00 = unpack_bf16(q0.x), f01 = unpack_bf16(q0.y);
      a0 += f00.x; a1 += f00.y; a2 += f01.x; a3 += f01.y;
    }
    st[lv * 13 + 4 * p + 0] = a0 + c0;
    st[lv * 13 + 4 * p + 1] = a1 + c1;
    st[lv * 13 + 4 * p + 2] = a2 + c2;
    st[lv * 13 + 4 * p + 3] = a3 + c3;
  }
  __syncthreads();
  if (tid < RB) {
    int v = b * RB + tid;
    if (v < N) {
      float d = dis[v];
      float vals[NCLS];
      float m = -1e30f;
#pragma unroll
      for (int c = 0; c < 5; ++c) {
        float2 sf = unpack_bf16(h2p[v * 6 + c]);
        float t0 = d * (st[tid * 13 + 2 * c] + sf.x) + b2s[2 * c];
        float t1 = d * (st[tid * 13 + 2 * c + 1] + sf.y) + b2s[2 * c + 1];
        vals[2 * c] = t0;
        vals[2 * c + 1] = t1;
        m = fmaxf(m, fmaxf(t0, t1));
      }
      float sum = 0.f;
#pragma unroll
      for (int c = 0; c < NCLS; ++c) sum += expf(vals[c] - m);
      float ls = logf(sum);
#pragma unroll
      for (int c = 0; c < NCLS; ++c) sto[tid * NCLS + c] = vals[c] - m - ls;
    }
  }
  __syncthreads();
  int nn = min(RB, N - b * RB);
  if (nn < 0) nn = 0;
  const int tot = nn * NCLS;
  const int obase = b * RB * NCLS;
  {
    const int tot4 = tot >> 2;
    float4* o4 = (float4*)(out + obase);
    for (int i = tid; i < tot4; i += 512) o4[i] = ((const float4*)sto)[i];
    for (int i = (tot4 << 2) + tid; i < tot; i += 512)
      out[obase + i] = sto[i];
  }
}

extern "C" void kernel_launch(void* const* d_in, const int* in_sizes, int n_in,
                              void* d_out, int out_size, void* d_ws,
                              size_t ws_size, hipStream_t stream) {
  const float* x = (const float*)d_in[0];
  const void* ei = d_in[1];
  const float* W1 = (const float*)d_in[2];
  const float* b1 = (const float*)d_in[3];
  const float* W2 = (const float*)d_in[4];
  const float* b2 = (const float*)d_in[5];
  float* out = (float*)d_out;

  const int N = in_sizes[0] / F_IN;  // 100000
  const int E = in_sizes[1] / 2;     // 3200000
  const int NB = (N + RB - 1) / RB;  // 782 buckets
  const int NPAD = NB * RB;

  // ws layout (4-byte words):
  int* flag = (int*)d_ws;                      // [16]
  int* cursor = flag + 16;                     // [NBMAX]
  unsigned* wfrag = (unsigned*)(cursor + NBMAX);  // [2048] 8KB W1 fragments
  unsigned* pk = wfrag + 2048;                 // [NB*CAP] ~14.4 MB
  int* off_g = (int*)(pk + (long long)NB * CAP);  // [NB*OFFS] ~0.4 MB
  float* dis = (float*)(off_g + (long long)NB * OFFS);  // [NPAD]
  unsigned* h1p = (unsigned*)(dis + NPAD);     // [8*NPAD] 3.2 MB (bf16 x16)
  unsigned* h2p = h1p + (long long)8 * NPAD;   // [6*NPAD] 2.4 MB (bf16 x12)
  // total ~21.5 MB

  k_prep<<<1, 1024, 0, stream>>>(ei, N, flag, cursor, NB, W1, wfrag);
  k_bucket<<<256, 1024, 0, stream>>>(ei, E, flag, cursor, pk, NB);
  k_sortgemm<<<NB, 512, 0, stream>>>(pk, cursor, off_g, dis, x, wfrag, h1p, N);
  k_bagg1<<<NB, 512, 0, stream>>>(pk, off_g, h1p, dis, W2, b1, h2p, N);
  k_bagg2<<<NB, 512, 0, stream>>>(pk, off_g, h2p, dis, b2, out, N);
}